// Round 8
// baseline (29.976 us; speedup 1.0000x reference)
//
#include <hip/hip_runtime.h>

// Output = Re(O @ H) per element: [Re H10, Re H11, Re H00, Re H01]
//   = [k*cos(2psi), h11, h00, k*cos(2psi)]
// k=(d2-d1)*c*s, h00=d1*c^2+d2*s^2, h11=d1*s^2+d2*c^2,
// d1=2*x1, d2=2*x2*(1-|x1|); delta (U[:,2]) cancels in H = U d U^H.
//
// Round-6 structure (27.2 us): block = 1024 elements, U staged via dense
// float4 loads -> LDS, thread t computes {base + j*256 + t} so every global
// access is instruction-coalesced (full 64B lines per wave op).
// This round: nontemporal on all global streams (each line touched once;
// full-line NT writes are safe — round 5's NT regression was the strided map).
#define TPB 256
#define ELEMS 4

typedef float f32x4 __attribute__((ext_vector_type(4)));

__global__ void __launch_bounds__(TPB) vo_kernel(
    const f32x4* __restrict__ U4,    // B*3/4 vec4
    const float* __restrict__ x1,
    const float* __restrict__ x2,
    f32x4* __restrict__ out4,        // B vec4
    int n)                           // B
{
    __shared__ float uS[TPB * ELEMS * 3];   // 12 KB: 3072 floats = 1024 elems of U

    const int base = blockIdx.x * (TPB * ELEMS);  // first element of this block
    const bool full = (base + TPB * ELEMS) <= n;  // uniform fast-path flag

    // Stage U: 3072 floats = 768 vec4, dense + coalesced, streaming (NT).
    {
        long long ub = (long long)base * 3 / 4;   // vec4 index
        long long u4_total = (3LL * n) / 4;
        f32x4* uS4 = reinterpret_cast<f32x4*>(uS);
        #pragma unroll
        for (int k = 0; k < 3; ++k) {
            long long idx = ub + threadIdx.x + TPB * k;
            if (full || idx < u4_total)
                uS4[threadIdx.x + TPB * k] = __builtin_nontemporal_load(&U4[idx]);
        }
    }
    __syncthreads();

    #pragma unroll
    for (int j = 0; j < ELEMS; ++j) {
        int local = j * TPB + threadIdx.x;   // 0..1023
        int e = base + local;                // global element
        if (!full && e >= n) break;

        float u0 = uS[3 * local + 0];        // psi
        float th = uS[3 * local + 1];        // theta
        float l1 = __builtin_nontemporal_load(&x1[e]);
        float l2 = __builtin_nontemporal_load(&x2[e]) * (1.0f - fabsf(l1));
        float d1 = 2.0f * l1;
        float d2 = 2.0f * l2;

        float st = __sinf(th);
        float ct = __cosf(th);
        float c2 = __cosf(2.0f * u0);

        float k   = (d2 - d1) * ct * st;
        float h00 = d1 * ct * ct + d2 * st * st;
        float h11 = d1 * st * st + d2 * ct * ct;
        float kr  = k * c2;

        f32x4 o = {kr, h11, h00, kr};
        __builtin_nontemporal_store(o, &out4[e]);
    }
}

extern "C" void kernel_launch(void* const* d_in, const int* in_sizes, int n_in,
                              void* d_out, int out_size, void* d_ws, size_t ws_size,
                              hipStream_t stream) {
    const f32x4* U4 = (const f32x4*)d_in[0];
    const float* x1 = (const float*)d_in[1];
    const float* x2 = (const float*)d_in[2];
    // d_in[3] is O (constant swap matrix) — folded into the kernel.
    f32x4* out4 = (f32x4*)d_out;

    int n = in_sizes[1];                    // B_SIZE
    int per_block = TPB * ELEMS;            // 1024
    int grid = (n + per_block - 1) / per_block;   // 4096
    vo_kernel<<<grid, TPB, 0, stream>>>(U4, x1, x2, out4, n);
}

// Round 9
// 27.421 us; speedup vs baseline: 1.0932x; 1.0932x over previous
//
#include <hip/hip_runtime.h>

// Output = Re(O @ H) per element: [Re H10, Re H11, Re H00, Re H01]
//   = [k*cos(2psi), h11, h00, k*cos(2psi)]
// k=(d2-d1)*c*s, h00=d1*c^2+d2*s^2, h11=d1*s^2+d2*c^2,
// d1=2*x1, d2=2*x2*(1-|x1|); delta (U[:,2]) cancels in H = U d U^H.
//
// Best structure (round 6, 27.2 us = 5.43 TB/s): block = 1024 elements,
// U staged via dense float4 loads -> LDS, thread t computes elements
// {base + j*256 + t} so every global access (x1/x2 dword loads, float4
// stores) is instruction-coalesced, full 64B lines per wave op.
// Verified-regressive variants — do NOT reapply:
//   - nontemporal hints on any stream (r5: +2.6x write amp strided; r8: +2.8us full-line)
//   - hoisting x1/x2 loads above __syncthreads (r7: +0.8us, live-range stretch)
#define TPB 256
#define ELEMS 4

typedef float f32x4 __attribute__((ext_vector_type(4)));

__global__ void __launch_bounds__(TPB) vo_kernel(
    const f32x4* __restrict__ U4,    // B*3/4 vec4
    const float* __restrict__ x1,
    const float* __restrict__ x2,
    f32x4* __restrict__ out4,        // B vec4
    int n)                           // B
{
    __shared__ float uS[TPB * ELEMS * 3];   // 12 KB: 3072 floats = 1024 elems of U

    int base = blockIdx.x * (TPB * ELEMS);  // first element of this block

    // Stage U: 3072 floats = 768 vec4, dense + coalesced.
    long long ub = (long long)base * 3 / 4;        // vec4 index
    long long u4_total = (3LL * n) / 4;
    f32x4* uS4 = reinterpret_cast<f32x4*>(uS);
    #pragma unroll
    for (int k = 0; k < 3; ++k) {
        long long idx = ub + threadIdx.x + TPB * k;
        if (idx < u4_total)
            uS4[threadIdx.x + TPB * k] = U4[idx];
    }
    __syncthreads();

    #pragma unroll
    for (int j = 0; j < ELEMS; ++j) {
        int local = j * TPB + threadIdx.x;   // 0..1023
        int e = base + local;                // global element
        if (e >= n) break;

        float u0 = uS[3 * local + 0];        // psi
        float th = uS[3 * local + 1];        // theta
        float l1 = x1[e];
        float l2 = x2[e] * (1.0f - fabsf(l1));
        float d1 = 2.0f * l1;
        float d2 = 2.0f * l2;

        float st = __sinf(th);
        float ct = __cosf(th);
        float c2 = __cosf(2.0f * u0);

        float k   = (d2 - d1) * ct * st;
        float h00 = d1 * ct * ct + d2 * st * st;
        float h11 = d1 * st * st + d2 * ct * ct;
        float kr  = k * c2;

        f32x4 o = {kr, h11, h00, kr};
        out4[e] = o;
    }
}

extern "C" void kernel_launch(void* const* d_in, const int* in_sizes, int n_in,
                              void* d_out, int out_size, void* d_ws, size_t ws_size,
                              hipStream_t stream) {
    const f32x4* U4 = (const f32x4*)d_in[0];
    const float* x1 = (const float*)d_in[1];
    const float* x2 = (const float*)d_in[2];
    // d_in[3] is O (constant swap matrix) — folded into the kernel.
    f32x4* out4 = (f32x4*)d_out;

    int n = in_sizes[1];                    // B_SIZE
    int per_block = TPB * ELEMS;            // 1024
    int grid = (n + per_block - 1) / per_block;   // 4096
    vo_kernel<<<grid, TPB, 0, stream>>>(U4, x1, x2, out4, n);
}